// Round 9
// baseline (97.718 us; speedup 1.0000x reference)
//
#include <hip/hip_runtime.h>

#define H_DIM 768
#define B_DIM 64
#define L_DIM 512
#define M_TOT (B_DIM*L_DIM)   // 32768
#define BM 128                // fallback tile
#define BN 128
#define BK 64
#define NB_CNT (H_DIM/BN)     // 6
#define KB_CNT (H_DIM/BK)     // 12
#define MB_CNT (M_TOT/BM)     // 256
#define TILE_HALFS (BM*BK)    // 8192 halfs (fallback W tile)

// ---- new GEMM geometry: BM=256, BN=128, BK=32 ----
#define KB32 24               // 768/32
#define MB256 128             // 32768/256
#define AT_H 8192             // A tile halfs: 256x32
#define WT_H 4096             // W tile halfs: 128x32
#define BUF_H 12288           // A 8192 + B 4096 = 24KB

typedef _Float16 f16x8 __attribute__((ext_vector_type(8)));
typedef float f32x4 __attribute__((ext_vector_type(4)));

// ws byte offsets
#define WS_W16   0u           // 768*768 halfs = 1179648 B (tiled, swizzle-baked)
#define WS_NUP   1179648u     // 6*32768 f32
#define WS_ALPHA 1966080u     // 32768 f32
#define WS_POOL  2097152u     // 8*64*768 f32
#define WS_AIMG  3670016u     // 32768*768 halfs (tiled, swizzle-baked)
#define WS_NEED_IMG (WS_AIMG + (size_t)M_TOT*H_DIM*2)

__device__ __forceinline__ void gload_lds16(const void* g, void* l) {
  __builtin_amdgcn_global_load_lds((const __attribute__((address_space(1))) void*)g,
                                   (__attribute__((address_space(3))) void*)l, 16, 0, 0);
}

__device__ __forceinline__ f16x8 cvt8(const float* src) {
  f32x4 x0 = *(const f32x4*)src;
  f32x4 x1 = *(const f32x4*)(src + 4);
  f16x8 h;
  h[0]=(_Float16)x0[0]; h[1]=(_Float16)x0[1]; h[2]=(_Float16)x0[2]; h[3]=(_Float16)x0[3];
  h[4]=(_Float16)x1[0]; h[5]=(_Float16)x1[1]; h[6]=(_Float16)x1[2]; h[7]=(_Float16)x1[3];
  return h;
}

// tanh(v) = 1 - 2/(exp2(2.885...*v)+1); limits give +-1 exactly.
__device__ __forceinline__ float fast_tanh(float v) {
  float e = __builtin_amdgcn_exp2f(v * 2.8853900817779268f);
  return 1.0f - 2.0f * __builtin_amdgcn_rcpf(e + 1.0f);
}

#define SBAR()  do { __builtin_amdgcn_sched_barrier(0); \
                     __builtin_amdgcn_s_barrier(); \
                     __builtin_amdgcn_sched_barrier(0); } while (0)

// ---------------- kernel 1a: W_fc -> fp16 tiles [128 x 32], swizzle sp^((row>>1)&3) ----
__global__ __launch_bounds__(256) void wconv32_kernel(const float* __restrict__ Wfc,
                                                      _Float16* __restrict__ W16) {
  int t = blockIdx.x;             // 0..143 : nb*24 + kb
  int nb = t / KB32, kb = t % KB32;
  _Float16* dst = W16 + (size_t)t * WT_H;
#pragma unroll
  for (int i = 0; i < 2; ++i) {
    int c = threadIdx.x + i * 256;        // 0..511 octets
    int row = c >> 2, sp = c & 3;
    int sl = sp ^ ((row >> 1) & 3);
    *(f16x8*)(dst + c*8) =
        cvt8(Wfc + (size_t)(nb*BN + row)*H_DIM + kb*32 + sl*8);
  }
}

// ---------------- kernel 1b: hidden_states -> fp16 tiles [256 x 32] ----------------
__global__ __launch_bounds__(256) void aconv32_kernel(const float* __restrict__ A,
                                                      _Float16* __restrict__ img) {
  int t = blockIdx.x;             // 0..3071 : mb*24 + kb
  int mb = t / KB32, kb = t % KB32;
  _Float16* dst = img + (size_t)t * AT_H;
#pragma unroll
  for (int i = 0; i < 4; ++i) {
    int c = threadIdx.x + i * 256;        // 0..1023 octets
    int row = c >> 2, sp = c & 3;
    int sl = sp ^ ((row >> 1) & 3);
    *(f16x8*)(dst + c*8) =
        cvt8(A + (size_t)(mb*256 + row)*H_DIM + kb*32 + sl*8);
  }
}

// ---------------- GEMM helpers (new geometry) ----------------
__device__ __forceinline__ void stage3(const _Float16* aT, const _Float16* wT,
                                       _Float16* buf, int tid) {
  gload_lds16(aT + tid*8,         buf + tid*8);
  gload_lds16(aT + (tid+512)*8,   buf + (tid+512)*8);
  gload_lds16(wT + tid*8,         buf + 8192 + tid*8);
}

__device__ __forceinline__ void rd_frags(const _Float16* base, const int aoff[4],
                                         const int boff[4], f16x8 af[4], f16x8 bf[4]) {
#pragma unroll
  for (int mi = 0; mi < 4; ++mi) af[mi] = *(const f16x8*)(base + aoff[mi]);
#pragma unroll
  for (int ni = 0; ni < 4; ++ni) bf[ni] = *(const f16x8*)(base + boff[ni]);
}

__device__ __forceinline__ void mfma16(const f16x8 af[4], const f16x8 bf[4],
                                       f32x4 acc[4][4]) {
  __builtin_amdgcn_s_setprio(1);
#pragma unroll
  for (int mi = 0; mi < 4; ++mi)
#pragma unroll
    for (int ni = 0; ni < 4; ++ni)
      acc[mi][ni] = __builtin_amdgcn_mfma_f32_16x16x32_f16(af[mi], bf[ni], acc[mi][ni], 0, 0, 0);
  __builtin_amdgcn_s_setprio(0);
}

// One pipelined step: tile tau = 24*P + j. FIN/FOUT = frag set parity (j&1 ... even->0).
#define PITER(P, j, FIN, FOUT) do {                                            \
    _Float16* bufc_ = ((j) & 1) ? b1 : b0;                                     \
    _Float16* bufn_ = ((j) & 1) ? b0 : b1;                                     \
    asm volatile("s_waitcnt lgkmcnt(0)" ::: "memory");                         \
    SBAR();                                           /* all waves read bufc_ */\
    if ((P) < 2 || (j) < 22) {                                                 \
      int j2_ = ((j) < 22) ? (j) + 2 : (j) - 22;                               \
      stage3(abase + (size_t)j2_ * AT_H, wS, bufc_, tid);                      \
      wS += WT_H;                                                              \
    }                                                                          \
    mfma16(af##FIN, bf##FIN, acc);                                             \
    if ((P) == 2 && (j) == 22) { asm volatile("s_waitcnt vmcnt(0)" ::: "memory"); } \
    else                       { asm volatile("s_waitcnt vmcnt(3)" ::: "memory"); } \
    SBAR();                                           /* tile tau+1 landed */  \
    rd_frags(bufn_, aoff, boff, af##FOUT, bf##FOUT);                           \
  } while (0)

// Per-pass epilogue: tanh + wnu-dot + LDS-transpose reduction + store (256 rows).
#define EPI(P) do {                                                            \
    float s16_[4][4];                                                          \
    _Pragma("unroll") for (int mi = 0; mi < 4; ++mi)                           \
    _Pragma("unroll") for (int r = 0; r < 4; ++r) {                            \
      float s_ = 0.f;                                                          \
      _Pragma("unroll") for (int ni = 0; ni < 4; ++ni)                         \
        s_ = fmaf(fast_tanh(acc[mi][ni][r] + bb[P][ni]), wn[P][ni], s_);       \
      s16_[mi][r] = s_;                                                        \
    }                                                                          \
    if (wc == 0) {                                                             \
      _Pragma("unroll") for (int mi = 0; mi < 4; ++mi)                         \
      _Pragma("unroll") for (int r = 0; r < 4; ++r)                            \
        scr[(wr*64 + mi*16 + lk*4 + r)*20 + lrow] = s16_[mi][r];               \
    }                                                                          \
    asm volatile("s_waitcnt lgkmcnt(0)" ::: "memory");                         \
    SBAR();                                                                    \
    float pa_ = 0.f;                                                           \
    if (tid < 256) {                                                           \
      const f32x4* sp_ = (const f32x4*)(scr + tid*20);                         \
      f32x4 q_ = sp_[0] + sp_[1] + sp_[2] + sp_[3];                            \
      pa_ = q_[0] + q_[1] + q_[2] + q_[3];                                     \
    }                                                                          \
    asm volatile("s_waitcnt lgkmcnt(0)" ::: "memory");                         \
    SBAR();                                                                    \
    if (wc == 1) {                                                             \
      _Pragma("unroll") for (int mi = 0; mi < 4; ++mi)                         \
      _Pragma("unroll") for (int r = 0; r < 4; ++r)                            \
        scr[(wr*64 + mi*16 + lk*4 + r)*20 + lrow] = s16_[mi][r];               \
    }                                                                          \
    asm volatile("s_waitcnt lgkmcnt(0)" ::: "memory");                         \
    SBAR();                                                                    \
    if (tid < 256) {                                                           \
      const f32x4* sp_ = (const f32x4*)(scr + tid*20);                         \
      f32x4 q_ = sp_[0] + sp_[1] + sp_[2] + sp_[3];                            \
      nup[(size_t)(nb0 + (P)) * M_TOT + m0 + tid] = pa_ + q_[0]+q_[1]+q_[2]+q_[3]; \
    }                                                                          \
  } while (0)

// ---------------- kernel 2: 256x128x32 fine-pipelined GEMM, multipass 3 ----------------
__global__ __launch_bounds__(512, 2) void gemm_nu_img_kernel(const _Float16* __restrict__ Aimg,
                                                             const _Float16* __restrict__ W16,
                                                             const float* __restrict__ bfc,
                                                             const float* __restrict__ wnu,
                                                             float* __restrict__ nup) {
  __shared__ __align__(16) _Float16 LS[2 * BUF_H];        // 48KB double buffer
  __shared__ __align__(16) float scr[256 * 20];           // 20KB reduce scratch

  int bid = blockIdx.x;           // 0..255
  int x = bid & 7, g = (bid >> 3) & 1, c = bid >> 4;
  int mb = c*8 + x;               // XCD-paired: (mb,g0) and (mb,g1) share bid%8
  int nb0 = g * 3;
  int m0 = mb * 256;
  int tid = threadIdx.x;
  int wv = tid >> 6, ln = tid & 63;
  int wr = wv >> 1, wc = wv & 1;  // 4M x 2N wave grid, 64x64 output each
  int lrow = ln & 15, lk = ln >> 4;

  f32x4 acc[4][4] = {};
  f16x8 af0[4], bf0[4], af1[4], bf1[4];
  const _Float16* abase = Aimg + (size_t)(mb * KB32) * AT_H;
  const _Float16* wbase = W16  + (size_t)(nb0 * KB32) * WT_H;
  _Float16* b0 = LS;
  _Float16* b1 = LS + BUF_H;

  // per-thread fragment offsets (halfs); slot swizzle constant per lane:
  // (row>>1)&3 == (lrow>>1)&3 since wr*64, mi*16 are multiples of 8
  int slot = (lk ^ ((lrow >> 1) & 3)) * 8;
  int aoff[4], boff[4];
#pragma unroll
  for (int mi = 0; mi < 4; ++mi) aoff[mi] = (wr*64 + mi*16 + lrow) * 32 + slot;
#pragma unroll
  for (int ni = 0; ni < 4; ++ni) boff[ni] = 8192 + (wc*64 + ni*16 + lrow) * 32 + slot;

  // epilogue constants: force materialization, then drain so vmcnt counts stay exact
  float wn[3][4], bb[3][4];
#pragma unroll
  for (int p = 0; p < 3; ++p) {
#pragma unroll
    for (int ni = 0; ni < 4; ++ni) {
      int cc = (nb0 + p)*BN + wc*64 + ni*16 + lrow;   // C/D col = lane&15 (m89-verified)
      wn[p][ni] = wnu[cc];
      bb[p][ni] = bfc[cc];
    }
    asm volatile("" :: "v"(wn[p][0]), "v"(wn[p][1]), "v"(wn[p][2]), "v"(wn[p][3]),
                       "v"(bb[p][0]), "v"(bb[p][1]), "v"(bb[p][2]), "v"(bb[p][3]));
  }
  asm volatile("s_waitcnt vmcnt(0)" ::: "memory");

  // prologue: tiles 0,1 in flight; tile 0 landed (tile 1's 3 loads outstanding)
  stage3(abase,        wbase,        b0, tid);
  stage3(abase + AT_H, wbase + WT_H, b1, tid);
  const _Float16* wS = wbase + 2 * WT_H;          // monotonic W cursor (72 tiles total)
  asm volatile("s_waitcnt vmcnt(3)" ::: "memory");
  SBAR();
  rd_frags(b0, aoff, boff, af0, bf0);             // tile 0

  // ---- pass 0 ----
#pragma unroll 1
  for (int jj = 0; jj < 12; ++jj) { PITER(0, 2*jj, 0, 1); PITER(0, 2*jj+1, 1, 0); }
  EPI(0);
#pragma unroll
  for (int mi = 0; mi < 4; ++mi)
#pragma unroll
    for (int ni = 0; ni < 4; ++ni) acc[mi][ni] = f32x4{0.f, 0.f, 0.f, 0.f};

  // ---- pass 1 ----
#pragma unroll 1
  for (int jj = 0; jj < 12; ++jj) { PITER(1, 2*jj, 0, 1); PITER(1, 2*jj+1, 1, 0); }
  EPI(1);
#pragma unroll
  for (int mi = 0; mi < 4; ++mi)
#pragma unroll
    for (int ni = 0; ni < 4; ++ni) acc[mi][ni] = f32x4{0.f, 0.f, 0.f, 0.f};

  // ---- pass 2 (tail peeled) ----
#pragma unroll 1
  for (int jj = 0; jj < 11; ++jj) { PITER(2, 2*jj, 0, 1); PITER(2, 2*jj+1, 1, 0); }
  PITER(2, 22, 0, 1);             // vmcnt(0); reads tile 23 frags into set 1
  mfma16(af1, bf1, acc);          // tile 23
  EPI(2);
}

// ---------------- fallback path (old 128x64 tile format) ----------------
__global__ __launch_bounds__(256) void wconv_old_kernel(const float* __restrict__ Wfc,
                                                        _Float16* __restrict__ W16) {
  int t = blockIdx.x;             // 0..71
  int nb = t / KB_CNT, kb = t % KB_CNT;
#pragma unroll
  for (int i = 0; i < 4; ++i) {
    int u = threadIdx.x + i * 256;
    int row = u >> 3, sp = u & 7;
    int sl = sp ^ (row & 7);
    *(f16x8*)(W16 + (size_t)t*TILE_HALFS + u*8) =
        cvt8(Wfc + (size_t)(nb*BN + row)*H_DIM + kb*BK + sl*8);
  }
}

__global__ __launch_bounds__(256) void gemm_nu_kernel(const float* __restrict__ A,
                                                      const _Float16* __restrict__ W16,
                                                      const float* __restrict__ bfc,
                                                      const float* __restrict__ wnu,
                                                      float* __restrict__ nup) {
  __shared__ __align__(16) _Float16 lsA[TILE_HALFS];
  __shared__ __align__(16) _Float16 lsB[TILE_HALFS];
  __shared__ float nred[2][BM];

  int bid = blockIdx.x;
  int nb = bid % NB_CNT;
  int mb = bid / NB_CNT;
  int m0 = mb * BM, n0 = nb * BN;
  int tid = threadIdx.x;
  int wv = tid >> 6, ln = tid & 63;
  int wr = wv >> 1, wc = wv & 1;
  int lrow = ln & 15, lk = ln >> 4;

  f32x4 acc[4][4] = {};
  const _Float16* wbase = W16 + (size_t)(nb * KB_CNT) * TILE_HALFS;

  for (int kb = 0; kb < KB_CNT; ++kb) {
    const _Float16* wt = wbase + (size_t)kb * TILE_HALFS;
    for (int i = 0; i < 4; ++i) {
      int e = (tid + i*256) * 8;
      gload_lds16(wt + e, lsB + e);
    }
    for (int i = 0; i < 4; ++i) {
      int u = tid + i * 256;
      int row = u >> 3, sl = u & 7;
      *(f16x8*)(lsA + row*BK + ((sl ^ (row & 7)) * 8)) =
          cvt8(A + (size_t)(m0 + row) * H_DIM + kb*BK + sl*8);
    }
    __syncthreads();
#pragma unroll
    for (int kk = 0; kk < 2; ++kk) {
      f16x8 af[4], bf[4];
      int s = kk*4 + lk;
#pragma unroll
      for (int mi = 0; mi < 4; ++mi) {
        int r = wr*64 + mi*16 + lrow;
        af[mi] = *(const f16x8*)(lsA + r*BK + ((s ^ (r & 7)) * 8));
      }
#pragma unroll
      for (int ni = 0; ni < 4; ++ni) {
        int r = wc*64 + ni*16 + lrow;
        bf[ni] = *(const f16x8*)(lsB + r*BK + ((s ^ (r & 7)) * 8));
      }
#pragma unroll
      for (int mi = 0; mi < 4; ++mi)
#pragma unroll
        for (int ni = 0; ni < 4; ++ni)
          acc[mi][ni] = __builtin_amdgcn_mfma_f32_16x16x32_f16(af[mi], bf[ni], acc[mi][ni], 0, 0, 0);
    }
    __syncthreads();
  }

  float wn[4], bb[4];
  for (int ni = 0; ni < 4; ++ni) {
    int cc = n0 + wc*64 + ni*16 + lrow;
    wn[ni] = wnu[cc];
    bb[ni] = bfc[cc];
  }
  for (int mi = 0; mi < 4; ++mi) {
    for (int r = 0; r < 4; ++r) {
      float s = 0.f;
      for (int ni = 0; ni < 4; ++ni)
        s = fmaf(fast_tanh(acc[mi][ni][r] + bb[ni]), wn[ni], s);
      for (int o = 1; o < 16; o <<= 1) s += __shfl_xor(s, o, 64);
      if (lrow == 0) nred[wc][wr*64 + mi*16 + lk*4 + r] = s;
    }
  }
  __syncthreads();
  if (tid < BM)
    nup[(size_t)nb * M_TOT + m0 + tid] = nred[0][tid] + nred[1][tid];
}

// ---------------- kernel 3: softmax over L per batch ----------------
__global__ __launch_bounds__(512) void softmax_kernel(const float* __restrict__ nup,
                                                      float* __restrict__ alphas) {
  int b = blockIdx.x;
  int l = threadIdx.x;
  int m = b * L_DIM + l;
  float v = 0.f;
  for (int nb = 0; nb < NB_CNT; ++nb) v += nup[(size_t)nb * M_TOT + m];
  __shared__ float smax[8], ssum[8];
  int w = l >> 6, ln = l & 63;
  float mx = v;
  for (int o = 1; o < 64; o <<= 1) mx = fmaxf(mx, __shfl_xor(mx, o, 64));
  if (ln == 0) smax[w] = mx;
  __syncthreads();
  mx = smax[0];
  for (int i = 1; i < 8; ++i) mx = fmaxf(mx, smax[i]);
  float e = __expf(v - mx);
  float sm = e;
  for (int o = 1; o < 64; o <<= 1) sm += __shfl_xor(sm, o, 64);
  if (ln == 0) ssum[w] = sm;
  __syncthreads();
  float tot = 0.f;
  for (int i = 0; i < 8; ++i) tot += ssum[i];
  alphas[m] = e / tot;
}

// ---------------- pooling from fp16 A-image (new [256x32] format) ----------------
__global__ __launch_bounds__(192) void pool1_img_kernel(const _Float16* __restrict__ img,
                                                        const float* __restrict__ alphas,
                                                        float* __restrict__ part) {
  int b = blockIdx.x >> 3;
  int lc = blockIdx.x & 7;
  int tid = threadIdx.x;
  int g = tid % 96, rp = tid / 96;      // g -> (kb, sl): h = kb*32 + sl*8 + j
  int kb = g >> 2, sl = g & 3;
  __shared__ float al[64];
  __shared__ float tmp[2][H_DIM];
  if (tid < 64) al[tid] = alphas[b * L_DIM + lc*64 + tid];
  __syncthreads();
  float s[8] = {};
  for (int l = rp; l < 64; l += 2) {
    int m = b * L_DIM + lc*64 + l;
    int mb = m >> 8, row = m & 255;
    const f16x8* src = (const f16x8*)(img + ((size_t)(mb*KB32 + kb))*AT_H
                                      + row*32 + ((sl ^ ((row >> 1) & 3)) * 8));
    f16x8 h = *src;
    float a = al[l];
#pragma unroll
    for (int j = 0; j < 8; ++j) s[j] = fmaf(a, (float)h[j], s[j]);
  }
#pragma unroll
  for (int j = 0; j < 8; ++j) tmp[rp][g*8 + j] = s[j];
  __syncthreads();
  float* dst = part + ((size_t)lc * B_DIM + b) * H_DIM + tid*4;
  f32x4 o;
#pragma unroll
  for (int q = 0; q < 4; ++q) o[q] = tmp[0][tid*4 + q] + tmp[1][tid*4 + q];
  *(f32x4*)dst = o;
}

// fallback pool1 on fp32 hs
__global__ __launch_bounds__(256) void pool1_kernel(const float* __restrict__ hs,
                                                    const float* __restrict__ alphas,
                                                    float* __restrict__ part) {
  int b = blockIdx.x >> 3;
  int lc = blockIdx.x & 7;
  int tid = threadIdx.x;
  __shared__ float al[64];
  if (tid < 64) al[tid] = alphas[b * L_DIM + lc*64 + tid];
  __syncthreads();
  const float* xp = hs + ((size_t)b * L_DIM + lc*64) * H_DIM;
  int h0 = tid * 3;
  float s0 = 0.f, s1 = 0.f, s2 = 0.f;
  for (int l = 0; l < 64; ++l) {
    float a = al[l];
    const float* r = xp + (size_t)l * H_DIM + h0;
    s0 += a * r[0]; s1 += a * r[1]; s2 += a * r[2];
  }
  float* dst = part + ((size_t)lc * B_DIM + b) * H_DIM + h0;
  dst[0] = s0; dst[1] = s1; dst[2] = s2;
}

__global__ __launch_bounds__(256) void pool2_kernel(const float* __restrict__ part,
                                                    float* __restrict__ out) {
  int i = blockIdx.x * 256 + threadIdx.x;
  float s = 0.f;
  for (int lc = 0; lc < 8; ++lc) s += part[(size_t)lc * (B_DIM * H_DIM) + i];
  out[i] = s;
}

extern "C" void kernel_launch(void* const* d_in, const int* in_sizes, int n_in,
                              void* d_out, int out_size, void* d_ws, size_t ws_size,
                              hipStream_t stream) {
  const float* hs  = (const float*)d_in[0];
  const float* Wfc = (const float*)d_in[1];
  const float* bfc = (const float*)d_in[2];
  const float* wnu = (const float*)d_in[3];
  float* out = (float*)d_out;
  char* ws = (char*)d_ws;
  _Float16* W16 = (_Float16*)(ws + WS_W16);
  float* nup    = (float*)(ws + WS_NUP);
  float* alphas = (float*)(ws + WS_ALPHA);
  float* part   = (float*)(ws + WS_POOL);

  bool img = (ws_size >= WS_NEED_IMG);
  _Float16* Aimg = (_Float16*)(ws + WS_AIMG);
  if (img) {
    wconv32_kernel<<<NB_CNT * KB32, 256, 0, stream>>>(Wfc, W16);
    aconv32_kernel<<<MB256 * KB32, 256, 0, stream>>>(hs, Aimg);
    gemm_nu_img_kernel<<<MB256 * 2, 512, 0, stream>>>(Aimg, W16, bfc, wnu, nup);
  } else {
    wconv_old_kernel<<<NB_CNT * KB_CNT, 256, 0, stream>>>(Wfc, W16);
    gemm_nu_kernel<<<MB_CNT * NB_CNT, 256, 0, stream>>>(hs, W16, bfc, wnu, nup);
  }
  softmax_kernel<<<B_DIM, 512, 0, stream>>>(nup, alphas);
  if (img) {
    pool1_img_kernel<<<B_DIM * 8, 192, 0, stream>>>(Aimg, alphas, part);
  } else {
    pool1_kernel<<<B_DIM * 8, 256, 0, stream>>>(hs, alphas, part);
  }
  pool2_kernel<<<192, 256, 0, stream>>>(part, out);
}

// Round 10
// 90.321 us; speedup vs baseline: 1.0819x; 1.0819x over previous
//
#include <hip/hip_runtime.h>

#define H_DIM 768
#define B_DIM 64
#define L_DIM 512
#define M_TOT (B_DIM*L_DIM)   // 32768
#define BM 128
#define BN 128
#define BK 64
#define NB_CNT (H_DIM/BN)     // 6
#define KB_CNT (H_DIM/BK)     // 12
#define MB_CNT (M_TOT/BM)     // 256
#define TILE_HALFS (BM*BK)    // 8192 halfs = 16KB
#define BUFH 16384            // halfs per LDS buffer (A 8192 + B 8192 = 32KB)

typedef _Float16 f16x8 __attribute__((ext_vector_type(8)));
typedef float f32x4 __attribute__((ext_vector_type(4)));

// ws byte offsets
#define WS_W16   0u           // 768*768 halfs (tiled, swizzle-baked)
#define WS_NUP   1179648u     // 6*32768 f32
#define WS_ALPHA 1966080u     // (unused now)
#define WS_POOL  2097152u     // 8*64*768 f32
#define WS_AIMG  3670016u     // 32768*768 halfs (tiled; written by gemm pass 0)
#define WS_NEED_IMG (WS_AIMG + (size_t)M_TOT*H_DIM*2)

__device__ __forceinline__ void gload_lds16(const void* g, void* l) {
  __builtin_amdgcn_global_load_lds((const __attribute__((address_space(1))) void*)g,
                                   (__attribute__((address_space(3))) void*)l, 16, 0, 0);
}

__device__ __forceinline__ f16x8 cvt8(const float* src) {
  f32x4 x0 = *(const f32x4*)src;
  f32x4 x1 = *(const f32x4*)(src + 4);
  f16x8 h;
  h[0]=(_Float16)x0[0]; h[1]=(_Float16)x0[1]; h[2]=(_Float16)x0[2]; h[3]=(_Float16)x0[3];
  h[4]=(_Float16)x1[0]; h[5]=(_Float16)x1[1]; h[6]=(_Float16)x1[2]; h[7]=(_Float16)x1[3];
  return h;
}

__device__ __forceinline__ f16x8 cvt8v(f32x4 x0, f32x4 x1) {
  f16x8 h;
  h[0]=(_Float16)x0[0]; h[1]=(_Float16)x0[1]; h[2]=(_Float16)x0[2]; h[3]=(_Float16)x0[3];
  h[4]=(_Float16)x1[0]; h[5]=(_Float16)x1[1]; h[6]=(_Float16)x1[2]; h[7]=(_Float16)x1[3];
  return h;
}

// tanh(v) = 1 - 2/(exp2(2.885...*v)+1); limits give +-1 exactly.
__device__ __forceinline__ float fast_tanh(float v) {
  float e = __builtin_amdgcn_exp2f(v * 2.8853900817779268f);
  return 1.0f - 2.0f * __builtin_amdgcn_rcpf(e + 1.0f);
}

#define SBAR()  do { __builtin_amdgcn_sched_barrier(0); \
                     __builtin_amdgcn_s_barrier(); \
                     __builtin_amdgcn_sched_barrier(0); } while (0)

// ---------------- kernel 1: W_fc fp32 -> fp16 tiled image (72 blocks) ----------------
__global__ __launch_bounds__(256) void wconv_kernel(const float* __restrict__ Wfc,
                                                    _Float16* __restrict__ W16) {
  int t = blockIdx.x;             // 0..71
  int nb = t / KB_CNT, kb = t % KB_CNT;
#pragma unroll
  for (int i = 0; i < 4; ++i) {
    int u = threadIdx.x + i * 256;
    int row = u >> 3, sp = u & 7;
    int sl = sp ^ (row & 7);
    *(f16x8*)(W16 + (size_t)t*TILE_HALFS + u*8) =
        cvt8(Wfc + (size_t)(nb*BN + row)*H_DIM + kb*BK + sl*8);
  }
}

// ---------------- GEMM helpers ----------------
__device__ __forceinline__ void stage128(const _Float16* at, const _Float16* wt,
                                         _Float16* Lb, int tid) {
#pragma unroll
  for (int i = 0; i < 4; ++i) {
    int e = (tid + i*256) * 8;
    gload_lds16(at + e, Lb + e);
  }
#pragma unroll
  for (int i = 0; i < 4; ++i) {
    int e = (tid + i*256) * 8;
    gload_lds16(wt + e, Lb + 8192 + e);
  }
}

__device__ __forceinline__ void rd_frags(const _Float16* base, const int aoff[4],
                                         const int boff[4], int slot,
                                         f16x8 af[4], f16x8 bf[4]) {
#pragma unroll
  for (int mi = 0; mi < 4; ++mi) af[mi] = *(const f16x8*)(base + aoff[mi] + slot);
#pragma unroll
  for (int ni = 0; ni < 4; ++ni) bf[ni] = *(const f16x8*)(base + boff[ni] + slot);
}

__device__ __forceinline__ void mfma16(const f16x8 af[4], const f16x8 bf[4],
                                       f32x4 acc[4][4]) {
  __builtin_amdgcn_s_setprio(1);
#pragma unroll
  for (int mi = 0; mi < 4; ++mi)
#pragma unroll
    for (int ni = 0; ni < 4; ++ni)
      acc[mi][ni] = __builtin_amdgcn_mfma_f32_16x16x32_f16(af[mi], bf[ni], acc[mi][ni], 0, 0, 0);
  __builtin_amdgcn_s_setprio(0);
}

// One pipelined iteration (passes 1,2). P=1: stage always (j<10 own tile j+2;
// j=10,11 next pass tiles 0,1). P=2: stage only j<10; j=10 drains.
#define PASS_ITER(P, j) do {                                                   \
    _Float16* bufc_ = ((j) & 1) ? b1 : b0;                                     \
    _Float16* bufn_ = ((j) & 1) ? b0 : b1;                                     \
    rd_frags(bufc_, aoff, boff, slot1, af1, bf1);                              \
    mfma16(af0, bf0, acc);                                                     \
    asm volatile("s_waitcnt lgkmcnt(0)" ::: "memory");                         \
    SBAR();                                                                    \
    if ((P) < 2 || (j) < 10) {                                                 \
      const _Float16* aS = abase + (size_t)(((j) < 10) ? (j) + 2 : (j) - 10) * TILE_HALFS; \
      stage128(aS, wS, bufc_, tid);                                            \
      wS += TILE_HALFS;                                                        \
    }                                                                          \
    if ((P) == 2 && (j) == 10) { asm volatile("s_waitcnt vmcnt(0)" ::: "memory"); } \
    else                       { asm volatile("s_waitcnt vmcnt(8)" ::: "memory"); } \
    SBAR();                                                                    \
    rd_frags(bufn_, aoff, boff, slot0, af0, bf0);                              \
    mfma16(af1, bf1, acc);                                                     \
  } while (0)

// Per-pass epilogue: tanh + wnu-dot + LDS-transpose reduction + store.
#define EPI(P) do {                                                            \
    float s16_[4][4];                                                          \
    _Pragma("unroll") for (int mi = 0; mi < 4; ++mi)                           \
    _Pragma("unroll") for (int r = 0; r < 4; ++r) {                            \
      float s_ = 0.f;                                                          \
      _Pragma("unroll") for (int ni = 0; ni < 4; ++ni)                         \
        s_ = fmaf(fast_tanh(acc[mi][ni][r] + bb[P][ni]), wn[P][ni], s_);       \
      s16_[mi][r] = s_;                                                        \
    }                                                                          \
    if (wc == 0) {                                                             \
      _Pragma("unroll") for (int mi = 0; mi < 4; ++mi)                         \
      _Pragma("unroll") for (int r = 0; r < 4; ++r)                            \
        scr[(wr*64 + mi*16 + lk*4 + r)*20 + lrow] = s16_[mi][r];               \
    }                                                                          \
    asm volatile("s_waitcnt lgkmcnt(0)" ::: "memory");                         \
    SBAR();                                                                    \
    float pa_ = 0.f;                                                           \
    if (tid < 128) {                                                           \
      const f32x4* sp_ = (const f32x4*)(scr + tid*20);                         \
      f32x4 q_ = sp_[0] + sp_[1] + sp_[2] + sp_[3];                            \
      pa_ = q_[0] + q_[1] + q_[2] + q_[3];                                     \
    }                                                                          \
    asm volatile("s_waitcnt lgkmcnt(0)" ::: "memory");                         \
    SBAR();                                                                    \
    if (wc == 1) {                                                             \
      _Pragma("unroll") for (int mi = 0; mi < 4; ++mi)                         \
      _Pragma("unroll") for (int r = 0; r < 4; ++r)                            \
        scr[(wr*64 + mi*16 + lk*4 + r)*20 + lrow] = s16_[mi][r];               \
    }                                                                          \
    asm volatile("s_waitcnt lgkmcnt(0)" ::: "memory");                         \
    SBAR();                                                                    \
    if (tid < 128) {                                                           \
      const f32x4* sp_ = (const f32x4*)(scr + tid*20);                         \
      f32x4 q_ = sp_[0] + sp_[1] + sp_[2] + sp_[3];                            \
      nup[(size_t)(nb0 + (P)) * M_TOT + m0 + tid] = pa_ + q_[0]+q_[1]+q_[2]+q_[3]; \
    }                                                                          \
  } while (0)

// ---------------- kernel 2: fused conv+GEMM, 3 nb passes per block (R8, proven) ----
__global__ __launch_bounds__(256, 2) void gemm_fused_kernel(const float* __restrict__ hs,
                                                            const _Float16* __restrict__ W16,
                                                            const float* __restrict__ bfc,
                                                            const float* __restrict__ wnu,
                                                            _Float16* __restrict__ Aimg,
                                                            float* __restrict__ nup) {
  __shared__ __align__(16) _Float16 LS[2 * BUFH];         // 64KB double buffer
  __shared__ __align__(16) float scr[128 * 20];           // 10KB reduce scratch

  int bid = blockIdx.x;
  int mb = bid & (MB_CNT - 1);    // 0..255
  int nb0 = (bid >> 8) * 3;       // 0 or 3
  int m0 = mb * BM;
  int tid = threadIdx.x;
  int wv = tid >> 6, ln = tid & 63;
  int wr = wv >> 1, wc = wv & 1;  // 2x2 wave grid, 64x64 output each
  int lrow = ln & 15, lk = ln >> 4;

  f32x4 acc[4][4] = {};
  f16x8 af0[4], bf0[4], af1[4], bf1[4];
  _Float16* imgb = Aimg + (size_t)(mb * KB_CNT) * TILE_HALFS;
  const _Float16* abase = imgb;
  const _Float16* wb0 = W16 + (size_t)(nb0 * KB_CNT) * TILE_HALFS;
  _Float16* b0 = LS;
  _Float16* b1 = LS + BUFH;

  int aoff[4], boff[4];
#pragma unroll
  for (int mi = 0; mi < 4; ++mi) aoff[mi] = (wr*64 + mi*16 + lrow) * 64;
#pragma unroll
  for (int ni = 0; ni < 4; ++ni) boff[ni] = 8192 + (wc*64 + ni*16 + lrow) * 64;
  int slot0 = ((0*4 + lk) ^ (lrow & 7)) * 8;
  int slot1 = ((1*4 + lk) ^ (lrow & 7)) * 8;

  float wn[3][4], bb[3][4];
#pragma unroll
  for (int p = 0; p < 3; ++p)
#pragma unroll
    for (int ni = 0; ni < 4; ++ni) {
      int c = (nb0 + p)*BN + wc*64 + ni*16 + lrow;  // C/D col = lane&15 (m89-verified)
      wn[p][ni] = wnu[c];
      bb[p][ni] = bfc[c];
    }
  asm volatile("s_waitcnt vmcnt(0)" ::: "memory");

  // ================= pass 0: fused convert+GEMM =================
  {
    int r0 = tid >> 3, sp = tid & 7;
    int sl = sp ^ (r0 & 7);                          // same sl for all 4 sub-rows (32 ≡ 0 mod 8)
    const float* asrc = hs + (size_t)(m0 + r0) * H_DIM + sl * 8;
    f32x4 R[8]; f16x8 H[4];
#pragma unroll
    for (int i = 0; i < 4; ++i) {
      int e = (tid + i*256) * 8;
      gload_lds16(wb0 + e, b0 + 8192 + e);
    }
#pragma unroll
    for (int i = 0; i < 4; ++i) {
      const float* p = asrc + (size_t)(32*i) * H_DIM;
      R[2*i] = *(const f32x4*)p; R[2*i+1] = *(const f32x4*)(p + 4);
    }
#pragma unroll
    for (int i = 0; i < 4; ++i) H[i] = cvt8v(R[2*i], R[2*i+1]);  // data-dep waits loads (W older -> also done)

#pragma unroll 1
    for (int kb = 0; kb < 12; ++kb) {
      _Float16* bufc = (kb & 1) ? b1 : b0;
      _Float16* bufn = (kb & 1) ? b0 : b1;
      _Float16* idst = imgb + (size_t)kb * TILE_HALFS;
#pragma unroll
      for (int i = 0; i < 4; ++i) {
        int e = (tid + i*256) * 8;
        *(f16x8*)(bufc + e) = H[i];                  // ds_write_b128
        *(f16x8*)(idst + e) = H[i];                  // global_store (image)
      }
      if (kb < 11) {
#pragma unroll
        for (int i = 0; i < 4; ++i) {
          int e = (tid + i*256) * 8;
          gload_lds16(wb0 + (size_t)(kb+1)*TILE_HALFS + e, bufn + 8192 + e);
        }
        const float* an = asrc + (size_t)(kb+1) * BK;
#pragma unroll
        for (int i = 0; i < 4; ++i) {
          const float* p = an + (size_t)(32*i) * H_DIM;
          R[2*i] = *(const f32x4*)p; R[2*i+1] = *(const f32x4*)(p + 4);
        }
      }
      asm volatile("s_waitcnt lgkmcnt(0)" ::: "memory");  // ds_writes committed
      SBAR();                                             // W(kb) landed (in-order: older than consumed A(kb))
      rd_frags(bufc, aoff, boff, slot0, af0, bf0);
      mfma16(af0, bf0, acc);
      rd_frags(bufc, aoff, boff, slot1, af1, bf1);
      mfma16(af1, bf1, acc);
      if (kb < 11) {
#pragma unroll
        for (int i = 0; i < 4; ++i) H[i] = cvt8v(R[2*i], R[2*i+1]);  // waits A(kb+1)
      }
      SBAR();                                             // protect bufn.B from next iter's gloads
    }
  }

  // ================= transition: prologue of pass 1 under EPI(0) =================
  const _Float16* w1b = W16 + (size_t)((nb0 + 1) * KB_CNT) * TILE_HALFS;
  stage128(abase,              w1b,              b0, tid);
  stage128(abase + TILE_HALFS, w1b + TILE_HALFS, b1, tid);
  const _Float16* wS = w1b + 2 * TILE_HALFS;      // monotonic W stage cursor
  EPI(0);
#pragma unroll
  for (int mi = 0; mi < 4; ++mi)
#pragma unroll
    for (int ni = 0; ni < 4; ++ni) acc[mi][ni] = f32x4{0.f, 0.f, 0.f, 0.f};
  asm volatile("s_waitcnt vmcnt(8)" ::: "memory");  // pass-0 stores + t0 landed (t1's 8 in flight)
  SBAR();
  rd_frags(b0, aoff, boff, slot0, af0, bf0);        // pass-1 t0 kk0

  // ---- pass 1 ----
#pragma unroll 1
  for (int j = 0; j < 12; ++j) PASS_ITER(1, j);
  EPI(1);
#pragma unroll
  for (int mi = 0; mi < 4; ++mi)
#pragma unroll
    for (int ni = 0; ni < 4; ++ni) acc[mi][ni] = f32x4{0.f, 0.f, 0.f, 0.f};

  // ---- pass 2 (last tile peeled) ----
#pragma unroll 1
  for (int j = 0; j < 11; ++j) PASS_ITER(2, j);
  rd_frags(b1, aoff, boff, slot1, af1, bf1);        // t11 kk1
  mfma16(af0, bf0, acc);                            // t11 kk0
  mfma16(af1, bf1, acc);                            // t11 kk1
  EPI(2);
}

// ---------------- fallback GEMM (fp32 A, in-kernel convert, 128^2) ----------------
__global__ __launch_bounds__(256) void gemm_nu_kernel(const float* __restrict__ A,
                                                      const _Float16* __restrict__ W16,
                                                      const float* __restrict__ bfc,
                                                      const float* __restrict__ wnu,
                                                      float* __restrict__ nup) {
  __shared__ __align__(16) _Float16 lsA[TILE_HALFS];
  __shared__ __align__(16) _Float16 lsB[TILE_HALFS];
  __shared__ float nred[2][BM];

  int bid = blockIdx.x;
  int nb = bid % NB_CNT;
  int mb = bid / NB_CNT;
  int m0 = mb * BM, n0 = nb * BN;
  int tid = threadIdx.x;
  int wv = tid >> 6, ln = tid & 63;
  int wr = wv >> 1, wc = wv & 1;
  int lrow = ln & 15, lk = ln >> 4;

  f32x4 acc[4][4] = {};
  const _Float16* wbase = W16 + (size_t)(nb * KB_CNT) * TILE_HALFS;

  for (int kb = 0; kb < KB_CNT; ++kb) {
    const _Float16* wt = wbase + (size_t)kb * TILE_HALFS;
    for (int i = 0; i < 4; ++i) {
      int e = (tid + i*256) * 8;
      gload_lds16(wt + e, lsB + e);
    }
    for (int i = 0; i < 4; ++i) {
      int u = tid + i * 256;
      int row = u >> 3, sl = u & 7;
      *(f16x8*)(lsA + row*BK + ((sl ^ (row & 7)) * 8)) =
          cvt8(A + (size_t)(m0 + row) * H_DIM + kb*BK + sl*8);
    }
    __syncthreads();
#pragma unroll
    for (int kk = 0; kk < 2; ++kk) {
      f16x8 af[4], bf[4];
      int s = kk*4 + lk;
#pragma unroll
      for (int mi = 0; mi < 4; ++mi) {
        int r = wr*64 + mi*16 + lrow;
        af[mi] = *(const f16x8*)(lsA + r*BK + ((s ^ (r & 7)) * 8));
      }
#pragma unroll
      for (int ni = 0; ni < 4; ++ni) {
        int r = wc*64 + ni*16 + lrow;
        bf[ni] = *(const f16x8*)(lsB + r*BK + ((s ^ (r & 7)) * 8));
      }
#pragma unroll
      for (int mi = 0; mi < 4; ++mi)
#pragma unroll
        for (int ni = 0; ni < 4; ++ni)
          acc[mi][ni] = __builtin_amdgcn_mfma_f32_16x16x32_f16(af[mi], bf[ni], acc[mi][ni], 0, 0, 0);
    }
    __syncthreads();
  }

  float wn[4], bb[4];
  for (int ni = 0; ni < 4; ++ni) {
    int c = n0 + wc*64 + ni*16 + lrow;
    wn[ni] = wnu[c];
    bb[ni] = bfc[c];
  }
  for (int mi = 0; mi < 4; ++mi) {
    for (int r = 0; r < 4; ++r) {
      float s = 0.f;
      for (int ni = 0; ni < 4; ++ni)
        s = fmaf(fast_tanh(acc[mi][ni][r] + bb[ni]), wn[ni], s);
      for (int o = 1; o < 16; o <<= 1) s += __shfl_xor(s, o, 64);
      if (lrow == 0) nred[wc][wr*64 + mi*16 + lk*4 + r] = s;
    }
  }
  __syncthreads();
  if (tid < BM)
    nup[(size_t)nb * M_TOT + m0 + tid] = nred[0][tid] + nred[1][tid];
}

// ---------------- fused softmax + pooling from fp16 A-image ----------------
// 512 blocks = (b, lc). Each block recomputes b's full softmax from nup (12KB read,
// duplicated 8x -> L2-free), then pools its 64-row chunk. Replaces softmax+pool1.
__global__ __launch_bounds__(256) void smpool_img_kernel(const _Float16* __restrict__ img,
                                                         const float* __restrict__ nup,
                                                         float* __restrict__ part) {
  int b = blockIdx.x >> 3;
  int lc = blockIdx.x & 7;
  int tid = threadIdx.x;
  __shared__ float al[512];
  __shared__ float rmax[4], rsum[4];
  __shared__ float tmp[2][H_DIM];

  // softmax over L=512 for batch b (256 threads x 2 elements)
  float v0 = 0.f, v1 = 0.f;
  int ms = b * L_DIM + tid;
#pragma unroll
  for (int nb = 0; nb < NB_CNT; ++nb) {
    v0 += nup[(size_t)nb * M_TOT + ms];
    v1 += nup[(size_t)nb * M_TOT + ms + 256];
  }
  int w = tid >> 6, ln = tid & 63;
  float mx = fmaxf(v0, v1);
  for (int o = 1; o < 64; o <<= 1) mx = fmaxf(mx, __shfl_xor(mx, o, 64));
  if (ln == 0) rmax[w] = mx;
  __syncthreads();
  mx = fmaxf(fmaxf(rmax[0], rmax[1]), fmaxf(rmax[2], rmax[3]));
  float e0 = __expf(v0 - mx), e1 = __expf(v1 - mx);
  float sm = e0 + e1;
  for (int o = 1; o < 64; o <<= 1) sm += __shfl_xor(sm, o, 64);
  if (ln == 0) rsum[w] = sm;
  __syncthreads();
  float tot = rsum[0] + rsum[1] + rsum[2] + rsum[3];
  al[tid] = e0 / tot;
  al[tid + 256] = e1 / tot;
  __syncthreads();

  // pool chunk lc (rows lc*64..lc*64+63), 192 active threads
  if (tid < 192) {
    int g = tid % 96, rp = tid / 96;
    int kb = g >> 3, sl = g & 7;
    float s[8] = {};
    for (int l = rp; l < 64; l += 2) {
      int m = b * L_DIM + lc*64 + l;
      int mb = m >> 7, row = m & 127;
      f16x8 h = *(const f16x8*)(img + ((size_t)(mb*KB_CNT + kb))*TILE_HALFS
                                + row*64 + ((sl ^ (row & 7)) * 8));
      float a = al[lc*64 + l];
#pragma unroll
      for (int j = 0; j < 8; ++j) s[j] = fmaf(a, (float)h[j], s[j]);
    }
#pragma unroll
    for (int j = 0; j < 8; ++j) tmp[rp][g*8 + j] = s[j];
  }
  __syncthreads();
  if (tid < 192) {
    float* dst = part + ((size_t)lc * B_DIM + b) * H_DIM + tid*4;
    f32x4 o;
#pragma unroll
    for (int q = 0; q < 4; ++q) o[q] = tmp[0][tid*4 + q] + tmp[1][tid*4 + q];
    *(f32x4*)dst = o;
  }
}

// fallback: fused softmax + pooling from fp32 hs
__global__ __launch_bounds__(256) void smpool_fb_kernel(const float* __restrict__ hs,
                                                        const float* __restrict__ nup,
                                                        float* __restrict__ part) {
  int b = blockIdx.x >> 3;
  int lc = blockIdx.x & 7;
  int tid = threadIdx.x;
  __shared__ float al[512];
  __shared__ float rmax[4], rsum[4];

  float v0 = 0.f, v1 = 0.f;
  int ms = b * L_DIM + tid;
#pragma unroll
  for (int nb = 0; nb < NB_CNT; ++nb) {
    v0 += nup[(size_t)nb * M_TOT + ms];
    v1 += nup[(size_t)nb * M_TOT + ms + 256];
  }
  int w = tid >> 6, ln = tid & 63;
  float mx = fmaxf(v0, v1);
  for (int o = 1; o < 64; o <<= 1) mx = fmaxf(mx, __shfl_xor(mx, o, 64));
  if (ln == 0) rmax[w] = mx;
  __syncthreads();
  mx = fmaxf(fmaxf(rmax[0], rmax[1]), fmaxf(rmax[2], rmax[3]));
  float e0 = __expf(v0 - mx), e1 = __expf(v1 - mx);
  float sm = e0 + e1;
  for (int o = 1; o < 64; o <<= 1) sm += __shfl_xor(sm, o, 64);
  if (ln == 0) rsum[w] = sm;
  __syncthreads();
  float tot = rsum[0] + rsum[1] + rsum[2] + rsum[3];
  al[tid] = e0 / tot;
  al[tid + 256] = e1 / tot;
  __syncthreads();

  const float* xp = hs + ((size_t)b * L_DIM + lc*64) * H_DIM;
  int h0 = tid * 3;
  float s0 = 0.f, s1 = 0.f, s2 = 0.f;
  for (int l = 0; l < 64; ++l) {
    float a = al[lc*64 + l];
    const float* r = xp + (size_t)l * H_DIM + h0;
    s0 += a * r[0]; s1 += a * r[1]; s2 += a * r[2];
  }
  float* dst = part + ((size_t)lc * B_DIM + b) * H_DIM + h0;
  dst[0] = s0; dst[1] = s1; dst[2] = s2;
}

__global__ __launch_bounds__(256) void pool2_kernel(const float* __restrict__ part,
                                                    float* __restrict__ out) {
  int i = blockIdx.x * 256 + threadIdx.x;
  float s = 0.f;
  for (int lc = 0; lc < 8; ++lc) s += part[(size_t)lc * (B_DIM * H_DIM) + i];
  out[i] = s;
}

extern "C" void kernel_launch(void* const* d_in, const int* in_sizes, int n_in,
                              void* d_out, int out_size, void* d_ws, size_t ws_size,
                              hipStream_t stream) {
  const float* hs  = (const float*)d_in[0];
  const float* Wfc = (const float*)d_in[1];
  const float* bfc = (const float*)d_in[2];
  const float* wnu = (const float*)d_in[3];
  float* out = (float*)d_out;
  char* ws = (char*)d_ws;
  _Float16* W16 = (_Float16*)(ws + WS_W16);
  float* nup    = (float*)(ws + WS_NUP);
  float* part   = (float*)(ws + WS_POOL);

  bool img = (ws_size >= WS_NEED_IMG);
  _Float16* Aimg = (_Float16*)(ws + WS_AIMG);
  wconv_kernel<<<NB_CNT * KB_CNT, 256, 0, stream>>>(Wfc, W16);
  if (img) {
    gemm_fused_kernel<<<MB_CNT * 2, 256, 0, stream>>>(hs, W16, bfc, wnu, Aimg, nup);
    smpool_img_kernel<<<B_DIM * 8, 256, 0, stream>>>(Aimg, nup, part);
  } else {
    gemm_nu_kernel<<<MB_CNT * NB_CNT, 256, 0, stream>>>(hs, W16, bfc, wnu, nup);
    smpool_fb_kernel<<<B_DIM * 8, 256, 0, stream>>>(hs, nup, part);
  }
  pool2_kernel<<<192, 256, 0, stream>>>(part, out);
}